// Round 1
// baseline (359.792 us; speedup 1.0000x reference)
//
#include <hip/hip_runtime.h>
#include <cstdint>
#include <cstddef>

#define B_   32
#define TIN  512
#define D_   384
#define F_   384
#define TOUT 4096

typedef __bf16 bf16x8 __attribute__((ext_vector_type(8)));
typedef float  f32x4  __attribute__((ext_vector_type(4)));
typedef unsigned short u16x8 __attribute__((ext_vector_type(8)));

__device__ __forceinline__ unsigned short f2bf(float f) {
  unsigned int u = __float_as_uint(f);
  u += 0x7fff + ((u >> 16) & 1);   // round-to-nearest-even
  return (unsigned short)(u >> 16);
}

// ---------------------------------------------------------------- prep
// [0,32)      cumsum+searchsorted -> idxv
// [32,+1152)  weight transpose: thread e reads w[e*3..+2], writes Wt[k][f][d]
#define PB_CUM 32
#define PB_W   1152
#define PB_TOT (PB_CUM + PB_W)

__global__ __launch_bounds__(256) void prep_all(
    const float* __restrict__ w1, const float* __restrict__ w2,
    unsigned short* __restrict__ Wt1, unsigned short* __restrict__ Wt2,
    const int* __restrict__ target, int* __restrict__ idxv) {
  int bx = blockIdx.x;
  int tid = threadIdx.x;

  if (bx < PB_CUM) {
    __shared__ int ends[512];
    __shared__ int ps[256];
    int b = bx;
    int a0 = target[b * TIN + 2 * tid];
    int a1 = target[b * TIN + 2 * tid + 1];
    ps[tid] = a0 + a1;
    __syncthreads();
    for (int off = 1; off < 256; off <<= 1) {
      int add = (tid >= off) ? ps[tid - off] : 0;
      __syncthreads();
      ps[tid] += add;
      __syncthreads();
    }
    int incl = ps[tid];
    ends[2 * tid + 1] = incl;
    ends[2 * tid]     = incl - a1;
    __syncthreads();
    for (int p = 0; p < 16; ++p) {
      int m = p * 256 + tid;
      int lo = 0, hi = 512;              // first j with ends[j] > m
      while (lo < hi) {
        int mid = (lo + hi) >> 1;
        if (ends[mid] <= m) lo = mid + 1; else hi = mid;
      }
      idxv[b * TOUT + m] = (lo < TIN) ? lo : -1;
    }
    return;
  }
  bx -= PB_CUM;

  {
    int g = bx * 256 + tid;                     // < 294912
    const int FD = F_ * D_;                     // 147456
    int which = g >= FD;
    const float* w = which ? w2 : w1;
    unsigned short* o = which ? Wt2 : Wt1;
    int e = g - which * FD;                     // f*D_+d
    o[e]          = f2bf(w[e * 3 + 0]);
    o[FD + e]     = f2bf(w[e * 3 + 1]);
    o[2 * FD + e] = f2bf(w[e * 3 + 2]);
  }
}

// ---------------------------------------------------------------- conv+LN+gather
// Grid 768 x 512thr. bx%3==0 -> conv tile (256 blocks: 64 rows x 384 cols);
// else gather (512 blocks: 128 contiguous out-rows of ONE batch each).
//
// Conv structure (barrier-free main loop):
//   1) reg-stage A rows t0-1..t0+64 (66x384 bf16, 50.7KB) into LDS with
//      XOR swizzle byte^=((row&7)<<4)  [row stride 768B = 16-way conflict
//      otherwise]; MODE0 converts f32 x on the fly (xp intermediate gone),
//      MODE1 reads bf16 h1; out-of-range rows -> zeros (no padded buffers).
//   2) one __syncthreads.
//   3) 36 k-steps: B-fragments loaded global->reg (wave-private columns —
//      LDS staging of B had zero cross-wave reuse), A-fragments via
//      swizzled ds_read_b128, 12 MFMA. No barriers; vmcnt pipelines.
//   4) epilogue: 2 groups of 32 rows through swizzled LDS (aliases A),
//      LN per row; MODE0: relu->bf16 h1, MODE1: dot(lin_w)+bias->dur.
template <int MODE>
__global__ __launch_bounds__(512, 4) void conv_fused(
    const float* __restrict__ xin,            // MODE0 A-source (f32)
    const unsigned short* __restrict__ hin,   // MODE1 A-source (bf16)
    const unsigned short* __restrict__ Wt,
    const float* __restrict__ bias,
    const float* __restrict__ gam, const float* __restrict__ bet,
    const float* __restrict__ lw, const float* __restrict__ lb,
    unsigned short* __restrict__ hout, float* __restrict__ dur,
    const float4* __restrict__ x4, const int* __restrict__ idxv,
    float4* __restrict__ out4, int half) {
  __shared__ __attribute__((aligned(16))) char smem[50688];  // 66*768

  const int bx  = blockIdx.x;
  const int tid = threadIdx.x;
  const int cbq = bx / 3;

  if (bx - cbq * 3 != 0) {
    // ---------------- gather: batch-local 128-row slab per block
    int gidx = bx - cbq - 1;                  // 0..511
    int b  = half * 16 + (gidx >> 5);
    int r0 = (gidx & 31) * 128;
    const int* idxp = idxv + b * TOUT + r0;
    const float4* xb = x4 + (size_t)b * (TIN * 96);
    float4* ob = out4 + ((size_t)b * TOUT + r0) * 96;
    #pragma unroll 8
    for (int it = 0; it < 24; ++it) {
      int j = it * 512 + tid;                 // 0..12287
      int row = j / 96;
      int c = j - row * 96;
      int id = idxp[row];
      float4 v = {0.f, 0.f, 0.f, 0.f};
      if (id >= 0) v = xb[id * 96 + c];
      ob[j] = v;
    }
    return;
  }

  // ---------------- conv tile: rows m0..m0+63, cols 0..383
  const int wave = tid >> 6;        // 0..7
  const int lane = tid & 63;
  const int quad = lane >> 4;
  const int l15  = lane & 15;
  const int wn   = wave * 48;
  const int m0   = cbq * 64;
  const int b    = m0 >> 9;         // 64-row tiles never cross batch
  const int t0   = m0 & 511;

  // ---- stage A once: 66 rows x 48 16B-chunks, swizzled
  for (int p = 0; p < 7; ++p) {
    int ch = p * 512 + tid;
    if (ch < 3168) {                          // 66*48
      int row = ch / 48;
      int ci  = ch - row * 48;
      int t   = t0 + row - 1;
      u16x8 val;
      if ((unsigned)t >= (unsigned)TIN) {
        val = (u16x8)0;
      } else if (MODE == 0) {
        const float4* xr = (const float4*)xin + ((size_t)(b * TIN + t)) * 96 + ci * 2;
        float4 v0 = xr[0], v1 = xr[1];
        val[0] = f2bf(v0.x); val[1] = f2bf(v0.y); val[2] = f2bf(v0.z); val[3] = f2bf(v0.w);
        val[4] = f2bf(v1.x); val[5] = f2bf(v1.y); val[6] = f2bf(v1.z); val[7] = f2bf(v1.w);
      } else {
        val = *(const u16x8*)(hin + ((size_t)(b * TIN + t)) * D_ + ci * 8);
      }
      unsigned int byte = ((unsigned int)(row * 768 + ci * 16)) ^ (((unsigned)row & 7u) << 4);
      *(u16x8*)(smem + byte) = val;
    }
  }
  __syncthreads();

  f32x4 acc[4][3];
  for (int i = 0; i < 4; ++i)
    for (int j = 0; j < 3; ++j)
      acc[i][j] = (f32x4){0.f, 0.f, 0.f, 0.f};

  // per-lane B base: col = wn + ni*16 + l15, k-bytes contiguous
  const unsigned short* Bb = Wt + (size_t)(wn + l15) * D_ + quad * 8;

  for (int kw = 0; kw < 3; ++kw) {
    const unsigned short* Bk = Bb + kw * (F_ * D_);
    const unsigned int rb = (unsigned int)((l15 + kw) * 768 + quad * 16);
    const unsigned int sw = (((unsigned)(l15 + kw)) & 7u) << 4;
    #pragma unroll 4
    for (int dc = 0; dc < 12; ++dc) {
      const int d0 = dc * 32;
      bf16x8 bv[3], av[4];
      for (int ni = 0; ni < 3; ++ni)
        bv[ni] = *(const bf16x8*)(Bk + ni * (16 * D_) + d0);
      for (int mi = 0; mi < 4; ++mi)
        av[mi] = *(const bf16x8*)(smem + ((rb + mi * 12288 + d0 * 2) ^ sw));
      for (int mi = 0; mi < 4; ++mi)
        for (int ni = 0; ni < 3; ++ni)
          acc[mi][ni] = __builtin_amdgcn_mfma_f32_16x16x32_bf16(av[mi], bv[ni], acc[mi][ni], 0, 0, 0);
    }
  }

  // ---- epilogue: per-lane column params for LN (cols lane + j*64)
  float gvv[6], bvv[6], lwv[6];
  for (int j = 0; j < 6; ++j) {
    int c = lane + j * 64;
    gvv[j] = gam[c];
    bvv[j] = bet[c];
    if (MODE == 1) lwv[j] = lw[c];
  }
  float bb[3];
  for (int ni = 0; ni < 3; ++ni) bb[ni] = bias[wn + ni * 16 + l15];

  for (int g = 0; g < 2; ++g) {               // 32-row groups
    __syncthreads();                          // all A-reads / prev group done
    for (int mi2 = 0; mi2 < 2; ++mi2) {
      int mi = g * 2 + mi2;
      for (int ni = 0; ni < 3; ++ni) {
        int cc = wn + ni * 16 + l15;
        for (int r = 0; r < 4; ++r) {
          int wr = mi2 * 16 + quad * 4 + r;   // C/D row = quad*4+r (+16*mi2)
          unsigned int byte = ((unsigned int)(wr * 1536 + cc * 4)) ^ ((((unsigned)wr >> 2) & 3u) << 4);
          *(float*)(smem + byte) = acc[mi][ni][r] + bb[ni];
        }
      }
    }
    __syncthreads();
    for (int rr = 0; rr < 4; ++rr) {          // 32 rows / 8 waves
      int lr = wave * 4 + rr;
      int grow = m0 + g * 32 + lr;            // global row = b*512 + t
      unsigned int swr = (((unsigned)lr >> 2) & 3u) << 4;
      float v[6], s = 0.f, ss = 0.f;
      for (int j = 0; j < 6; ++j) {
        unsigned int byte = ((unsigned int)(lr * 1536 + (lane + j * 64) * 4)) ^ swr;
        v[j] = *(const float*)(smem + byte);
        s += v[j];
        ss += v[j] * v[j];
      }
      for (int off = 32; off; off >>= 1) {
        s  += __shfl_xor(s, off);
        ss += __shfl_xor(ss, off);
      }
      float mean = s * (1.f / 384.f);
      float var  = ss * (1.f / 384.f) - mean * mean;
      float rstd = rsqrtf(var + 1e-5f);
      if (MODE == 0) {
        unsigned short* o = hout + ((size_t)(b * TIN + (grow & 511))) * D_;
        for (int j = 0; j < 6; ++j) {
          float y = (v[j] - mean) * rstd * gvv[j] + bvv[j];
          y = y > 0.f ? y : 0.f;
          o[lane + j * 64] = f2bf(y);
        }
      } else {
        float a = 0.f;
        for (int j = 0; j < 6; ++j) {
          float y = (v[j] - mean) * rstd * gvv[j] + bvv[j];
          y = y > 0.f ? y : 0.f;
          a += y * lwv[j];
        }
        for (int off = 32; off; off >>= 1) a += __shfl_xor(a, off);
        if (lane == 0) dur[grow] = a + lb[0];
      }
    }
  }
}

// ---------------------------------------------------------------- launch
extern "C" void kernel_launch(void* const* d_in, const int* in_sizes, int n_in,
                              void* d_out, int out_size, void* d_ws, size_t ws_size,
                              hipStream_t stream) {
  const float* x      = (const float*)d_in[0];
  const int*   target = (const int*)d_in[1];
  const float* w1  = (const float*)d_in[3];
  const float* b1  = (const float*)d_in[4];
  const float* g1  = (const float*)d_in[5];
  const float* be1 = (const float*)d_in[6];
  const float* w2  = (const float*)d_in[7];
  const float* b2  = (const float*)d_in[8];
  const float* g2  = (const float*)d_in[9];
  const float* be2 = (const float*)d_in[10];
  const float* lw  = (const float*)d_in[11];
  const float* lb  = (const float*)d_in[12];

  float* out = (float*)d_out;
  float* dur = out + (size_t)B_ * TOUT * D_;   // outputs concatenated flat

  char* ws = (char*)d_ws;
  unsigned short* h1   = (unsigned short*)(ws);             // 12,582,912 B
  unsigned short* Wt1  = (unsigned short*)(ws + 12582912);  //    884,736 B
  unsigned short* Wt2  = (unsigned short*)(ws + 13467648);  //    884,736 B
  int*            idxv = (int*)(ws + 14352384);             //    524,288 B

  prep_all<<<dim3(PB_TOT), dim3(256), 0, stream>>>(
      w1, w2, Wt1, Wt2, target, idxv);
  conv_fused<0><<<dim3(768), dim3(512), 0, stream>>>(
      x, nullptr, Wt1, b1, g1, be1, nullptr, nullptr,
      h1, nullptr, (const float4*)x, idxv, (float4*)out, 0);
  conv_fused<1><<<dim3(768), dim3(512), 0, stream>>>(
      nullptr, h1, Wt2, b2, g2, be2, lw, lb,
      nullptr, dur, (const float4*)x, idxv, (float4*)out, 1);
}

// Round 2
// 335.574 us; speedup vs baseline: 1.0722x; 1.0722x over previous
//
#include <hip/hip_runtime.h>
#include <cstdint>
#include <cstddef>

#define B_   32
#define TIN  512
#define D_   384
#define F_   384
#define TOUT 4096

typedef __bf16 bf16x8 __attribute__((ext_vector_type(8)));
typedef float  f32x4  __attribute__((ext_vector_type(4)));
typedef unsigned short u16x8 __attribute__((ext_vector_type(8)));

__device__ __forceinline__ unsigned short f2bf(float f) {
  unsigned int u = __float_as_uint(f);
  u += 0x7fff + ((u >> 16) & 1);   // round-to-nearest-even
  return (unsigned short)(u >> 16);
}

__device__ __forceinline__ void load16_to_lds(const void* g, void* l) {
  __builtin_amdgcn_global_load_lds(
      (const __attribute__((address_space(1))) unsigned int*)g,
      (__attribute__((address_space(3))) unsigned int*)l, 16, 0, 0);
}

// ---------------------------------------------------------------- prep
// [0,32)      cumsum+searchsorted -> idxv
// [32,+1152)  weight transpose: thread e reads w[e*3..+2], writes Wt[k][f][d]
#define PB_CUM 32
#define PB_W   1152
#define PB_TOT (PB_CUM + PB_W)

__global__ __launch_bounds__(256) void prep_all(
    const float* __restrict__ w1, const float* __restrict__ w2,
    unsigned short* __restrict__ Wt1, unsigned short* __restrict__ Wt2,
    const int* __restrict__ target, int* __restrict__ idxv) {
  int bx = blockIdx.x;
  int tid = threadIdx.x;

  if (bx < PB_CUM) {
    __shared__ int ends[512];
    __shared__ int ps[256];
    int b = bx;
    int a0 = target[b * TIN + 2 * tid];
    int a1 = target[b * TIN + 2 * tid + 1];
    ps[tid] = a0 + a1;
    __syncthreads();
    for (int off = 1; off < 256; off <<= 1) {
      int add = (tid >= off) ? ps[tid - off] : 0;
      __syncthreads();
      ps[tid] += add;
      __syncthreads();
    }
    int incl = ps[tid];
    ends[2 * tid + 1] = incl;
    ends[2 * tid]     = incl - a1;
    __syncthreads();
    for (int p = 0; p < 16; ++p) {
      int m = p * 256 + tid;
      int lo = 0, hi = 512;              // first j with ends[j] > m
      while (lo < hi) {
        int mid = (lo + hi) >> 1;
        if (ends[mid] <= m) lo = mid + 1; else hi = mid;
      }
      idxv[b * TOUT + m] = (lo < TIN) ? lo : -1;
    }
    return;
  }
  bx -= PB_CUM;

  {
    int g = bx * 256 + tid;                     // < 294912
    const int FD = F_ * D_;                     // 147456
    int which = g >= FD;
    const float* w = which ? w2 : w1;
    unsigned short* o = which ? Wt2 : Wt1;
    int e = g - which * FD;                     // f*D_+d
    o[e]          = f2bf(w[e * 3 + 0]);
    o[FD + e]     = f2bf(w[e * 3 + 1]);
    o[2 * FD + e] = f2bf(w[e * 3 + 2]);
  }
}

// ---------------------------------------------------------------- mega kernel
// Grid 1280 x 512thr. bx%5==0 -> conv block (256: conv1+LN+relu+conv2+LN+dot
// for 64 output rows, h1 never leaves LDS); else gather (1024 slabs of 128
// contiguous out-rows).
//
// Conv block:
//   LDS: A region 82 rows x 768B (62,976B; rows 0..67 = x[t0-2..t0+65] bf16,
//        swizzled byte^=((row&7)<<4); later aliased by h1 rows 0..65),
//        B region 2 x 24,576B double-buffer (Wt k-step tiles via
//        global_load_lds; buf0 aliased as 24KB f32 epilogue scratch).
//   conv1: 80-row 5x3 MFMA tile (rows 66..79 garbage, never used), one
//   __syncthreads per k-step (stage next -> compute cur -> barrier).
//   Epilogue1: bias+LN+relu per row -> h1 bf16 in LDS (boundary rows t=-1 /
//   t=512 forced to zero = conv2 padding). conv2: 4x3 tile from h1, same B
//   pipeline from Wt2. Epilogue2: bias+LN+relu+dot(lin_w)+lb -> dur.
__global__ __launch_bounds__(512, 1) void mega(
    const unsigned short* __restrict__ Wt1, const unsigned short* __restrict__ Wt2,
    const float* __restrict__ b1, const float* __restrict__ g1, const float* __restrict__ be1,
    const float* __restrict__ b2, const float* __restrict__ g2, const float* __restrict__ be2,
    const float* __restrict__ lw, const float* __restrict__ lb,
    float* __restrict__ dur,
    const float4* __restrict__ x4, const int* __restrict__ idxv,
    float4* __restrict__ out4) {
  __shared__ __attribute__((aligned(16))) char smem[112128];
  char* As = smem;                 // 82*768 = 62,976 ; h1 aliases [0,50688)
  char* Bs = smem + 62976;         // 2 x 24,576

  const int bx  = blockIdx.x;
  const int tid = threadIdx.x;
  const int cb  = bx / 5;

  if (bx - cb * 5 != 0) {
    // ---------------- gather: batch-local 128-row slab per block
    int gidx = bx - cb - 1;                   // 0..1023
    int b  = gidx >> 5;
    int r0 = (gidx & 31) * 128;
    const int* idxp = idxv + b * TOUT + r0;
    const f32x4* xb = (const f32x4*)(x4 + (size_t)b * (TIN * 96));
    f32x4* ob = (f32x4*)(out4 + ((size_t)b * TOUT + r0) * 96);
    #pragma unroll 8
    for (int it = 0; it < 24; ++it) {
      int j = it * 512 + tid;                 // 0..12287
      int row = j / 96;
      int c = j - row * 96;
      int id = idxp[row];
      f32x4 v = {0.f, 0.f, 0.f, 0.f};
      if (id >= 0) v = xb[id * 96 + c];
      __builtin_nontemporal_store(v, ob + j); // out never re-read: keep L2 for x/Wt
    }
    return;
  }

  // ---------------- conv block
  const int wave = tid >> 6;        // 0..7
  const int lane = tid & 63;
  const int quad = lane >> 4;
  const int l15  = lane & 15;
  const int wn   = wave * 48;
  const int m0   = cb * 64;
  const int b    = m0 >> 9;         // 64-row tiles never cross batch
  const int t0   = m0 & 511;
  const int arow = tid >> 2;        // 0..127
  const int acol = (tid & 3) * 8;

  // ---- stage A once: 68 rows x 48 16B-chunks, swizzled
  for (int p = 0; p < 7; ++p) {
    int ch = p * 512 + tid;
    if (ch < 3264) {                          // 68*48
      int row = ch / 48;
      int ci  = ch - row * 48;
      int t   = t0 - 2 + row;
      u16x8 val;
      if ((unsigned)t >= (unsigned)TIN) {
        val = (u16x8)0;
      } else {
        const float4* xr = (const float4*)x4 + ((size_t)(b * TIN + t)) * 96 + ci * 2;
        float4 v0 = xr[0], v1 = xr[1];
        val[0] = f2bf(v0.x); val[1] = f2bf(v0.y); val[2] = f2bf(v0.z); val[3] = f2bf(v0.w);
        val[4] = f2bf(v1.x); val[5] = f2bf(v1.y); val[6] = f2bf(v1.z); val[7] = f2bf(v1.w);
      }
      unsigned int byte = ((unsigned int)(row * 768 + ci * 16)) ^ (((unsigned)row & 7u) << 4);
      *(u16x8*)(As + byte) = val;
    }
  }

  // ---- B staging helper: 384x32 bf16 tile for k-step kc into buffer buf
  auto stageB = [&](const unsigned short* __restrict__ Wt, int kc, int buf) {
    int kw = kc / 12;
    int d0 = (kc - kw * 12) * 32;
    const unsigned short* src = Wt + (size_t)(kw * F_ + arow) * D_ + d0 + acol;
    char* dst = Bs + buf * 24576 + wave * 1024;
    for (int r = 0; r < 3; ++r)
      load16_to_lds(src + (size_t)(r * 128) * D_, dst + r * 8192);
  };

  // ================ conv1: 80-row tile (66 valid), acc 5x3
  f32x4 acc1[5][3];
  for (int i = 0; i < 5; ++i)
    for (int j = 0; j < 3; ++j)
      acc1[i][j] = (f32x4){0.f, 0.f, 0.f, 0.f};

  stageB(Wt1, 0, 0);
  __syncthreads();
  int cur = 0;
  #pragma unroll 1
  for (int kc = 0; kc < 36; ++kc) {
    if (kc < 35) stageB(Wt1, kc + 1, cur ^ 1);
    int kw = kc / 12;
    int d0 = (kc - kw * 12) * 32;
    const char* Bc = Bs + cur * 24576;
    bf16x8 bv[3];
    for (int ni = 0; ni < 3; ++ni)
      bv[ni] = *(const bf16x8*)(Bc + (wn + ni * 16 + l15) * 64 + quad * 16);
    int rb = l15 + kw;
    unsigned int sw = (((unsigned)rb) & 7u) << 4;
    unsigned int base = (unsigned int)(rb * 768 + d0 * 2 + quad * 16);
    bf16x8 av[5];
    for (int mi = 0; mi < 5; ++mi)
      av[mi] = *(const bf16x8*)(As + ((base + mi * 12288) ^ sw));
    for (int mi = 0; mi < 5; ++mi)
      for (int ni = 0; ni < 3; ++ni)
        acc1[mi][ni] = __builtin_amdgcn_mfma_f32_16x16x32_bf16(av[mi], bv[ni], acc1[mi][ni], 0, 0, 0);
    __syncthreads();
    cur ^= 1;
  }

  // ================ epilogue 1: bias + LN + relu -> h1 (bf16, LDS, aliases A)
  {
    float gv[6], bev[6];
    for (int j = 0; j < 6; ++j) {
      int c = lane + j * 64;
      gv[j] = g1[c]; bev[j] = be1[c];
    }
    float bb[3];
    for (int ni = 0; ni < 3; ++ni) bb[ni] = b1[wn + ni * 16 + l15];
    char* scr = Bs;                            // buf0 as 24KB f32 scratch

    for (int mi = 0; mi < 5; ++mi) {
      __syncthreads();                         // prev reads / conv1 done
      for (int ni = 0; ni < 3; ++ni) {
        int cc = wn + ni * 16 + l15;
        for (int r = 0; r < 4; ++r) {
          int wr = quad * 4 + r;               // C/D row = quad*4+r
          unsigned int byte = ((unsigned int)(wr * 1536 + cc * 4)) ^ ((((unsigned)wr >> 2) & 3u) << 4);
          *(float*)(scr + byte) = acc1[mi][ni][r] + bb[ni];
        }
      }
      __syncthreads();
      for (int rr = 0; rr < 2; ++rr) {
        int lr = wave * 2 + rr;
        int h = mi * 16 + lr;                  // h1 row index (0..65 valid)
        if (h >= 66) continue;                 // wave-uniform branch
        unsigned int swr = ((((unsigned)lr) >> 2) & 3u) << 4;
        float v[6], s = 0.f, ss = 0.f;
        for (int j = 0; j < 6; ++j) {
          unsigned int byte = ((unsigned int)(lr * 1536 + (lane + j * 64) * 4)) ^ swr;
          v[j] = *(const float*)(scr + byte);
          s += v[j]; ss += v[j] * v[j];
        }
        for (int off = 32; off; off >>= 1) {
          s  += __shfl_xor(s, off);
          ss += __shfl_xor(ss, off);
        }
        float mean = s * (1.f / 384.f);
        float var  = ss * (1.f / 384.f) - mean * mean;
        float rstd = rsqrtf(var + 1e-5f);
        int th = t0 - 1 + h;                   // global h1 time index
        bool valid = (unsigned)th < (unsigned)TIN;  // t=-1 / t=512 -> zero pad
        unsigned int hb = (((unsigned)h) & 7u) << 4;
        for (int j = 0; j < 6; ++j) {
          float y = (v[j] - mean) * rstd * gv[j] + bev[j];
          y = y > 0.f ? y : 0.f;
          if (!valid) y = 0.f;
          unsigned int byte = ((unsigned int)(h * 768 + (lane + j * 64) * 2)) ^ hb;
          *(unsigned short*)(As + byte) = f2bf(y);
        }
      }
    }
  }

  // ================ conv2: 64-row tile from h1 (LDS), acc 4x3
  __syncthreads();                             // scratch reads + h1 writes done
  f32x4 acc2[4][3];
  for (int i = 0; i < 4; ++i)
    for (int j = 0; j < 3; ++j)
      acc2[i][j] = (f32x4){0.f, 0.f, 0.f, 0.f};

  stageB(Wt2, 0, 0);
  __syncthreads();
  cur = 0;
  #pragma unroll 1
  for (int kc = 0; kc < 36; ++kc) {
    if (kc < 35) stageB(Wt2, kc + 1, cur ^ 1);
    int kw = kc / 12;
    int d0 = (kc - kw * 12) * 32;
    const char* Bc = Bs + cur * 24576;
    bf16x8 bv[3];
    for (int ni = 0; ni < 3; ++ni)
      bv[ni] = *(const bf16x8*)(Bc + (wn + ni * 16 + l15) * 64 + quad * 16);
    int rb = l15 + kw;                         // h1 row = m + kw, m = mi*16+l15
    unsigned int sw = (((unsigned)rb) & 7u) << 4;
    unsigned int base = (unsigned int)(rb * 768 + d0 * 2 + quad * 16);
    bf16x8 av[4];
    for (int mi = 0; mi < 4; ++mi)
      av[mi] = *(const bf16x8*)(As + ((base + mi * 12288) ^ sw));
    for (int mi = 0; mi < 4; ++mi)
      for (int ni = 0; ni < 3; ++ni)
        acc2[mi][ni] = __builtin_amdgcn_mfma_f32_16x16x32_bf16(av[mi], bv[ni], acc2[mi][ni], 0, 0, 0);
    __syncthreads();
    cur ^= 1;
  }

  // ================ epilogue 2: bias + LN + relu + dot(lin_w) + lb -> dur
  {
    float gv[6], bev[6], lwv[6];
    for (int j = 0; j < 6; ++j) {
      int c = lane + j * 64;
      gv[j] = g2[c]; bev[j] = be2[c]; lwv[j] = lw[c];
    }
    float bb[3];
    for (int ni = 0; ni < 3; ++ni) bb[ni] = b2[wn + ni * 16 + l15];
    float lbv = lb[0];
    char* scr = Bs;

    for (int mi = 0; mi < 4; ++mi) {
      __syncthreads();
      for (int ni = 0; ni < 3; ++ni) {
        int cc = wn + ni * 16 + l15;
        for (int r = 0; r < 4; ++r) {
          int wr = quad * 4 + r;
          unsigned int byte = ((unsigned int)(wr * 1536 + cc * 4)) ^ ((((unsigned)wr >> 2) & 3u) << 4);
          *(float*)(scr + byte) = acc2[mi][ni][r] + bb[ni];
        }
      }
      __syncthreads();
      for (int rr = 0; rr < 2; ++rr) {
        int lr = wave * 2 + rr;
        int m = mi * 16 + lr;                  // 0..63, all valid
        unsigned int swr = ((((unsigned)lr) >> 2) & 3u) << 4;
        float v[6], s = 0.f, ss = 0.f;
        for (int j = 0; j < 6; ++j) {
          unsigned int byte = ((unsigned int)(lr * 1536 + (lane + j * 64) * 4)) ^ swr;
          v[j] = *(const float*)(scr + byte);
          s += v[j]; ss += v[j] * v[j];
        }
        for (int off = 32; off; off >>= 1) {
          s  += __shfl_xor(s, off);
          ss += __shfl_xor(ss, off);
        }
        float mean = s * (1.f / 384.f);
        float var  = ss * (1.f / 384.f) - mean * mean;
        float rstd = rsqrtf(var + 1e-5f);
        float a = 0.f;
        for (int j = 0; j < 6; ++j) {
          float y = (v[j] - mean) * rstd * gv[j] + bev[j];
          y = y > 0.f ? y : 0.f;
          a += y * lwv[j];
        }
        for (int off = 32; off; off >>= 1) a += __shfl_xor(a, off);
        if (lane == 0) dur[m0 + m] = a + lbv;
      }
    }
  }
}

// ---------------------------------------------------------------- launch
extern "C" void kernel_launch(void* const* d_in, const int* in_sizes, int n_in,
                              void* d_out, int out_size, void* d_ws, size_t ws_size,
                              hipStream_t stream) {
  const float* x      = (const float*)d_in[0];
  const int*   target = (const int*)d_in[1];
  const float* w1  = (const float*)d_in[3];
  const float* b1  = (const float*)d_in[4];
  const float* g1  = (const float*)d_in[5];
  const float* be1 = (const float*)d_in[6];
  const float* w2  = (const float*)d_in[7];
  const float* b2  = (const float*)d_in[8];
  const float* g2  = (const float*)d_in[9];
  const float* be2 = (const float*)d_in[10];
  const float* lw  = (const float*)d_in[11];
  const float* lb  = (const float*)d_in[12];

  float* out = (float*)d_out;
  float* dur = out + (size_t)B_ * TOUT * D_;   // outputs concatenated flat

  char* ws = (char*)d_ws;
  unsigned short* Wt1  = (unsigned short*)(ws);             // 884,736 B
  unsigned short* Wt2  = (unsigned short*)(ws + 884736);    // 884,736 B
  int*            idxv = (int*)(ws + 1769472);              // 524,288 B

  prep_all<<<dim3(PB_TOT), dim3(256), 0, stream>>>(
      w1, w2, Wt1, Wt2, target, idxv);
  mega<<<dim3(1280), dim3(512), 0, stream>>>(
      Wt1, Wt2, b1, g1, be1, b2, g2, be2, lw, lb,
      dur, (const float4*)x, idxv, (float4*)out);
}

// Round 3
// 331.067 us; speedup vs baseline: 1.0868x; 1.0136x over previous
//
#include <hip/hip_runtime.h>
#include <cstdint>
#include <cstddef>

#define B_   32
#define TIN  512
#define D_   384
#define F_   384
#define TOUT 4096

typedef __bf16 bf16x8 __attribute__((ext_vector_type(8)));
typedef float  f32x4  __attribute__((ext_vector_type(4)));
typedef unsigned short u16x8 __attribute__((ext_vector_type(8)));

__device__ __forceinline__ unsigned short f2bf(float f) {
  unsigned int u = __float_as_uint(f);
  u += 0x7fff + ((u >> 16) & 1);   // round-to-nearest-even
  return (unsigned short)(u >> 16);
}

__device__ __forceinline__ void load16_to_lds(const void* g, void* l) {
  __builtin_amdgcn_global_load_lds(
      (const __attribute__((address_space(1))) unsigned int*)g,
      (__attribute__((address_space(3))) unsigned int*)l, 16, 0, 0);
}

// ---------------------------------------------------------------- gather+prep
// Grid 3200 x 256thr, ~3.3KB LDS -> 8 blocks/CU (32 waves/CU).
// bx <  2048 : gather slab = 64 contiguous out-rows of one batch.
//              Block self-computes the batch cumsum (no idxv buffer / no
//              prep dependency), binary-searches its 64 rows, then streams
//              64x96 float4 nontemporal stores (98KB).
// bx >= 2048 : weight transpose (1152 blocks): thread e reads w[e*3..+2],
//              writes Wt[k][f][d] bf16. Completes before conv launch by
//              stream order.
#define GB 2048

__global__ __launch_bounds__(256) void gather_prep(
    const float* __restrict__ w1, const float* __restrict__ w2,
    unsigned short* __restrict__ Wt1, unsigned short* __restrict__ Wt2,
    const int* __restrict__ target,
    const f32x4* __restrict__ x4, f32x4* __restrict__ out4) {
  int bx = blockIdx.x;
  int tid = threadIdx.x;

  if (bx < GB) {
    __shared__ int ends[512];
    __shared__ int ps[256];
    __shared__ int idx_s[64];
    int b  = bx >> 6;                         // 64 slabs per batch
    int r0 = (bx & 63) * 64;
    int a0 = target[b * TIN + 2 * tid];
    int a1 = target[b * TIN + 2 * tid + 1];
    ps[tid] = a0 + a1;
    __syncthreads();
    for (int off = 1; off < 256; off <<= 1) {
      int add = (tid >= off) ? ps[tid - off] : 0;
      __syncthreads();
      ps[tid] += add;
      __syncthreads();
    }
    int incl = ps[tid];
    ends[2 * tid + 1] = incl;
    ends[2 * tid]     = incl - a1;
    __syncthreads();
    if (tid < 64) {
      int m = r0 + tid;
      int lo = 0, hi = 512;                   // first j with ends[j] > m
      while (lo < hi) {
        int mid = (lo + hi) >> 1;
        if (ends[mid] <= m) lo = mid + 1; else hi = mid;
      }
      idx_s[tid] = (lo < TIN) ? lo : -1;
    }
    __syncthreads();
    const f32x4* xb = x4 + (size_t)b * (TIN * 96);
    f32x4* ob = out4 + ((size_t)b * TOUT + r0) * 96;
    #pragma unroll 4
    for (int it = 0; it < 24; ++it) {
      int j = it * 256 + tid;                 // 0..6143
      int row = j / 96;
      int c = j - row * 96;
      int id = idx_s[row];
      f32x4 v = {0.f, 0.f, 0.f, 0.f};
      if (id >= 0) v = xb[id * 96 + c];
      __builtin_nontemporal_store(v, ob + j); // out never re-read
    }
    return;
  }
  bx -= GB;

  {
    int g = bx * 256 + tid;                   // < 294912
    const int FD = F_ * D_;                   // 147456
    int which = g >= FD;
    const float* w = which ? w2 : w1;
    unsigned short* o = which ? Wt2 : Wt1;
    int e = g - which * FD;                   // f*D_+d
    o[e]          = f2bf(w[e * 3 + 0]);
    o[FD + e]     = f2bf(w[e * 3 + 1]);
    o[2 * FD + e] = f2bf(w[e * 3 + 2]);
  }
}

// ---------------------------------------------------------------- conv kernel
// 256 blocks x 512thr x 112KB LDS (1 block/CU, all 256 resident at once).
// Per block: conv1+LN+relu -> h1 (LDS only) -> conv2+LN+dot -> dur, for 64
// output rows. Same proven structure as round-2 mega conv path.
__global__ __launch_bounds__(512, 1) void conv(
    const unsigned short* __restrict__ Wt1, const unsigned short* __restrict__ Wt2,
    const float* __restrict__ b1, const float* __restrict__ g1, const float* __restrict__ be1,
    const float* __restrict__ b2, const float* __restrict__ g2, const float* __restrict__ be2,
    const float* __restrict__ lw, const float* __restrict__ lb,
    float* __restrict__ dur, const float4* __restrict__ x4) {
  __shared__ __attribute__((aligned(16))) char smem[112128];
  char* As = smem;                 // 82*768 = 62,976 ; h1 aliases [0,50688)
  char* Bs = smem + 62976;         // 2 x 24,576

  const int tid = threadIdx.x;
  const int cb  = blockIdx.x;

  const int wave = tid >> 6;        // 0..7
  const int lane = tid & 63;
  const int quad = lane >> 4;
  const int l15  = lane & 15;
  const int wn   = wave * 48;
  const int m0   = cb * 64;
  const int b    = m0 >> 9;         // 64-row tiles never cross batch
  const int t0   = m0 & 511;
  const int arow = tid >> 2;        // 0..127
  const int acol = (tid & 3) * 8;

  // ---- stage A once: 68 rows x 48 16B-chunks, swizzled
  for (int p = 0; p < 7; ++p) {
    int ch = p * 512 + tid;
    if (ch < 3264) {                          // 68*48
      int row = ch / 48;
      int ci  = ch - row * 48;
      int t   = t0 - 2 + row;
      u16x8 val;
      if ((unsigned)t >= (unsigned)TIN) {
        val = (u16x8)0;
      } else {
        const float4* xr = (const float4*)x4 + ((size_t)(b * TIN + t)) * 96 + ci * 2;
        float4 v0 = xr[0], v1 = xr[1];
        val[0] = f2bf(v0.x); val[1] = f2bf(v0.y); val[2] = f2bf(v0.z); val[3] = f2bf(v0.w);
        val[4] = f2bf(v1.x); val[5] = f2bf(v1.y); val[6] = f2bf(v1.z); val[7] = f2bf(v1.w);
      }
      unsigned int byte = ((unsigned int)(row * 768 + ci * 16)) ^ (((unsigned)row & 7u) << 4);
      *(u16x8*)(As + byte) = val;
    }
  }

  // ---- B staging helper: 384x32 bf16 tile for k-step kc into buffer buf
  auto stageB = [&](const unsigned short* __restrict__ Wt, int kc, int buf) {
    int kw = kc / 12;
    int d0 = (kc - kw * 12) * 32;
    const unsigned short* src = Wt + (size_t)(kw * F_ + arow) * D_ + d0 + acol;
    char* dst = Bs + buf * 24576 + wave * 1024;
    for (int r = 0; r < 3; ++r)
      load16_to_lds(src + (size_t)(r * 128) * D_, dst + r * 8192);
  };

  // ================ conv1: 80-row tile (66 valid), acc 5x3
  f32x4 acc1[5][3];
  for (int i = 0; i < 5; ++i)
    for (int j = 0; j < 3; ++j)
      acc1[i][j] = (f32x4){0.f, 0.f, 0.f, 0.f};

  stageB(Wt1, 0, 0);
  __syncthreads();
  int cur = 0;
  #pragma unroll 1
  for (int kc = 0; kc < 36; ++kc) {
    if (kc < 35) stageB(Wt1, kc + 1, cur ^ 1);
    int kw = kc / 12;
    int d0 = (kc - kw * 12) * 32;
    const char* Bc = Bs + cur * 24576;
    bf16x8 bv[3];
    for (int ni = 0; ni < 3; ++ni)
      bv[ni] = *(const bf16x8*)(Bc + (wn + ni * 16 + l15) * 64 + quad * 16);
    int rb = l15 + kw;
    unsigned int sw = (((unsigned)rb) & 7u) << 4;
    unsigned int base = (unsigned int)(rb * 768 + d0 * 2 + quad * 16);
    bf16x8 av[5];
    for (int mi = 0; mi < 5; ++mi)
      av[mi] = *(const bf16x8*)(As + ((base + mi * 12288) ^ sw));
    for (int mi = 0; mi < 5; ++mi)
      for (int ni = 0; ni < 3; ++ni)
        acc1[mi][ni] = __builtin_amdgcn_mfma_f32_16x16x32_bf16(av[mi], bv[ni], acc1[mi][ni], 0, 0, 0);
    __syncthreads();
    cur ^= 1;
  }

  // ================ epilogue 1: bias + LN + relu -> h1 (bf16, LDS, aliases A)
  {
    float gv[6], bev[6];
    for (int j = 0; j < 6; ++j) {
      int c = lane + j * 64;
      gv[j] = g1[c]; bev[j] = be1[c];
    }
    float bb[3];
    for (int ni = 0; ni < 3; ++ni) bb[ni] = b1[wn + ni * 16 + l15];
    char* scr = Bs;                            // buf0 as 24KB f32 scratch

    for (int mi = 0; mi < 5; ++mi) {
      __syncthreads();                         // prev reads / conv1 done
      for (int ni = 0; ni < 3; ++ni) {
        int cc = wn + ni * 16 + l15;
        for (int r = 0; r < 4; ++r) {
          int wr = quad * 4 + r;               // C/D row = quad*4+r
          unsigned int byte = ((unsigned int)(wr * 1536 + cc * 4)) ^ ((((unsigned)wr >> 2) & 3u) << 4);
          *(float*)(scr + byte) = acc1[mi][ni][r] + bb[ni];
        }
      }
      __syncthreads();
      for (int rr = 0; rr < 2; ++rr) {
        int lr = wave * 2 + rr;
        int h = mi * 16 + lr;                  // h1 row index (0..65 valid)
        if (h >= 66) continue;                 // wave-uniform branch
        unsigned int swr = ((((unsigned)lr) >> 2) & 3u) << 4;
        float v[6], s = 0.f, ss = 0.f;
        for (int j = 0; j < 6; ++j) {
          unsigned int byte = ((unsigned int)(lr * 1536 + (lane + j * 64) * 4)) ^ swr;
          v[j] = *(const float*)(scr + byte);
          s += v[j]; ss += v[j] * v[j];
        }
        for (int off = 32; off; off >>= 1) {
          s  += __shfl_xor(s, off);
          ss += __shfl_xor(ss, off);
        }
        float mean = s * (1.f / 384.f);
        float var  = ss * (1.f / 384.f) - mean * mean;
        float rstd = rsqrtf(var + 1e-5f);
        int th = t0 - 1 + h;                   // global h1 time index
        bool valid = (unsigned)th < (unsigned)TIN;  // t=-1 / t=512 -> zero pad
        unsigned int hb = (((unsigned)h) & 7u) << 4;
        for (int j = 0; j < 6; ++j) {
          float y = (v[j] - mean) * rstd * gv[j] + bev[j];
          y = y > 0.f ? y : 0.f;
          if (!valid) y = 0.f;
          unsigned int byte = ((unsigned int)(h * 768 + (lane + j * 64) * 2)) ^ hb;
          *(unsigned short*)(As + byte) = f2bf(y);
        }
      }
    }
  }

  // ================ conv2: 64-row tile from h1 (LDS), acc 4x3
  __syncthreads();                             // scratch reads + h1 writes done
  f32x4 acc2[4][3];
  for (int i = 0; i < 4; ++i)
    for (int j = 0; j < 3; ++j)
      acc2[i][j] = (f32x4){0.f, 0.f, 0.f, 0.f};

  stageB(Wt2, 0, 0);
  __syncthreads();
  cur = 0;
  #pragma unroll 1
  for (int kc = 0; kc < 36; ++kc) {
    if (kc < 35) stageB(Wt2, kc + 1, cur ^ 1);
    int kw = kc / 12;
    int d0 = (kc - kw * 12) * 32;
    const char* Bc = Bs + cur * 24576;
    bf16x8 bv[3];
    for (int ni = 0; ni < 3; ++ni)
      bv[ni] = *(const bf16x8*)(Bc + (wn + ni * 16 + l15) * 64 + quad * 16);
    int rb = l15 + kw;                         // h1 row = m + kw, m = mi*16+l15
    unsigned int sw = (((unsigned)rb) & 7u) << 4;
    unsigned int base = (unsigned int)(rb * 768 + d0 * 2 + quad * 16);
    bf16x8 av[4];
    for (int mi = 0; mi < 4; ++mi)
      av[mi] = *(const bf16x8*)(As + ((base + mi * 12288) ^ sw));
    for (int mi = 0; mi < 4; ++mi)
      for (int ni = 0; ni < 3; ++ni)
        acc2[mi][ni] = __builtin_amdgcn_mfma_f32_16x16x32_bf16(av[mi], bv[ni], acc2[mi][ni], 0, 0, 0);
    __syncthreads();
    cur ^= 1;
  }

  // ================ epilogue 2: bias + LN + relu + dot(lin_w) + lb -> dur
  {
    float gv[6], bev[6], lwv[6];
    for (int j = 0; j < 6; ++j) {
      int c = lane + j * 64;
      gv[j] = g2[c]; bev[j] = be2[c]; lwv[j] = lw[c];
    }
    float bb[3];
    for (int ni = 0; ni < 3; ++ni) bb[ni] = b2[wn + ni * 16 + l15];
    float lbv = lb[0];
    char* scr = Bs;

    for (int mi = 0; mi < 4; ++mi) {
      __syncthreads();
      for (int ni = 0; ni < 3; ++ni) {
        int cc = wn + ni * 16 + l15;
        for (int r = 0; r < 4; ++r) {
          int wr = quad * 4 + r;
          unsigned int byte = ((unsigned int)(wr * 1536 + cc * 4)) ^ ((((unsigned)wr >> 2) & 3u) << 4);
          *(float*)(scr + byte) = acc2[mi][ni][r] + bb[ni];
        }
      }
      __syncthreads();
      for (int rr = 0; rr < 2; ++rr) {
        int lr = wave * 2 + rr;
        int m = mi * 16 + lr;                  // 0..63, all valid
        unsigned int swr = ((((unsigned)lr) >> 2) & 3u) << 4;
        float v[6], s = 0.f, ss = 0.f;
        for (int j = 0; j < 6; ++j) {
          unsigned int byte = ((unsigned int)(lr * 1536 + (lane + j * 64) * 4)) ^ swr;
          v[j] = *(const float*)(scr + byte);
          s += v[j]; ss += v[j] * v[j];
        }
        for (int off = 32; off; off >>= 1) {
          s  += __shfl_xor(s, off);
          ss += __shfl_xor(ss, off);
        }
        float mean = s * (1.f / 384.f);
        float var  = ss * (1.f / 384.f) - mean * mean;
        float rstd = rsqrtf(var + 1e-5f);
        float a = 0.f;
        for (int j = 0; j < 6; ++j) {
          float y = (v[j] - mean) * rstd * gv[j] + bev[j];
          y = y > 0.f ? y : 0.f;
          a += y * lwv[j];
        }
        for (int off = 32; off; off >>= 1) a += __shfl_xor(a, off);
        if (lane == 0) dur[m0 + m] = a + lbv;
      }
    }
  }
}

// ---------------------------------------------------------------- launch
extern "C" void kernel_launch(void* const* d_in, const int* in_sizes, int n_in,
                              void* d_out, int out_size, void* d_ws, size_t ws_size,
                              hipStream_t stream) {
  const float* x      = (const float*)d_in[0];
  const int*   target = (const int*)d_in[1];
  const float* w1  = (const float*)d_in[3];
  const float* b1  = (const float*)d_in[4];
  const float* g1  = (const float*)d_in[5];
  const float* be1 = (const float*)d_in[6];
  const float* w2  = (const float*)d_in[7];
  const float* b2  = (const float*)d_in[8];
  const float* g2  = (const float*)d_in[9];
  const float* be2 = (const float*)d_in[10];
  const float* lw  = (const float*)d_in[11];
  const float* lb  = (const float*)d_in[12];

  float* out = (float*)d_out;
  float* dur = out + (size_t)B_ * TOUT * D_;   // outputs concatenated flat

  char* ws = (char*)d_ws;
  unsigned short* Wt1  = (unsigned short*)(ws);             // 884,736 B
  unsigned short* Wt2  = (unsigned short*)(ws + 884736);    // 884,736 B

  gather_prep<<<dim3(GB + 1152), dim3(256), 0, stream>>>(
      w1, w2, Wt1, Wt2, target, (const f32x4*)x, (f32x4*)out);
  conv<<<dim3(256), dim3(512), 0, stream>>>(
      Wt1, Wt2, b1, g1, be1, b2, g2, be2, lw, lb, dur, (const float4*)x);
}

// Round 5
// 283.499 us; speedup vs baseline: 1.2691x; 1.1678x over previous
//
#include <hip/hip_runtime.h>
#include <cstdint>
#include <cstddef>

#define B_   32
#define TIN  512
#define D_   384
#define F_   384
#define TOUT 4096

typedef __bf16 bf16x8 __attribute__((ext_vector_type(8)));
typedef float  f32x4  __attribute__((ext_vector_type(4)));
typedef unsigned short u16x8 __attribute__((ext_vector_type(8)));

__device__ __forceinline__ unsigned short f2bf(float f) {
  unsigned int u = __float_as_uint(f);
  u += 0x7fff + ((u >> 16) & 1);   // round-to-nearest-even
  return (unsigned short)(u >> 16);
}

// ---------------------------------------------------------------- prep (weights)
// 1152 blocks x 256: thread e reads w[e*3..+2] (f32, [F][D][K]), writes
// Wt[k][f][d] bf16. Gather cumsum is self-computed in the fused kernel.
__global__ __launch_bounds__(256) void prep_w(
    const float* __restrict__ w1, const float* __restrict__ w2,
    unsigned short* __restrict__ Wt1, unsigned short* __restrict__ Wt2) {
  int g = blockIdx.x * 256 + threadIdx.x;     // < 294912
  const int FD = F_ * D_;                     // 147456
  int which = g >= FD;
  const float* w = which ? w2 : w1;
  unsigned short* o = which ? Wt2 : Wt1;
  int e = g - which * FD;                     // f*D_+d
  o[e]          = f2bf(w[e * 3 + 0]);
  o[FD + e]     = f2bf(w[e * 3 + 1]);
  o[2 * FD + e] = f2bf(w[e * 3 + 2]);
}

// ---------------------------------------------------------------- fused kernel
// Grid 1280 x 512thr, LDS 68,736B -> 2 blocks/CU, VGPR capped 128 (bounds 512,4).
// bx < 256  : conv block (conv1+LN+relu in LDS -> conv2+LN+dot -> dur, 64 rows).
//             Barrier-free MFMA loops: A from swizzled LDS (ds_read_b128),
//             B global->reg with 1-step prefetch (Wt is L2-resident; per-wave
//             columns had zero cross-wave reuse, so LDS-staging B was waste).
//             LN via quad-shfl partials + 5.7KB stats region (no 24KB transpose).
// bx >= 256 : gather block: 128 contiguous out-rows of one batch; in-block
//             cumsum of target (512-scan), binary search, 196KB NT stores.
#define NCONV 256
#define NGATH 1024

__global__ __launch_bounds__(512, 4) void fused(
    const unsigned short* __restrict__ Wt1, const unsigned short* __restrict__ Wt2,
    const float* __restrict__ b1, const float* __restrict__ g1, const float* __restrict__ be1,
    const float* __restrict__ b2, const float* __restrict__ g2, const float* __restrict__ be2,
    const float* __restrict__ lw, const float* __restrict__ lb,
    float* __restrict__ dur, const int* __restrict__ target,
    const f32x4* __restrict__ x4, f32x4* __restrict__ out4) {
  __shared__ __attribute__((aligned(16))) char smem[68736];
  // conv: As [82 rows x 768B) = [0,62976) (x bf16 swizzled; h1 aliases rows 0..65)
  //       stats [80][8][2] f32 = [62976,68096) ; stats2 [80][2] f32 = [68096,68736)
  // gather: ends[512] int = [0,2048) ; idx_s[128] int = [2048,2560)

  const int tid = threadIdx.x;
  const int bx  = blockIdx.x;

  if (bx >= NCONV) {
    // ---------------- gather
    int gi = bx - NCONV;                      // 0..1023
    int* ends  = (int*)smem;
    int* idx_s = (int*)(smem + 2048);
    int b  = gi >> 5;
    int r0 = (gi & 31) * 128;
    ends[tid] = target[b * TIN + tid];
    __syncthreads();
    for (int off = 1; off < 512; off <<= 1) { // inclusive scan over 512
      int add = (tid >= off) ? ends[tid - off] : 0;
      __syncthreads();
      ends[tid] += add;
      __syncthreads();
    }
    if (tid < 128) {
      int m = r0 + tid;
      int lo = 0, hi = 512;                   // first j with ends[j] > m
      while (lo < hi) {
        int mid = (lo + hi) >> 1;
        if (ends[mid] <= m) lo = mid + 1; else hi = mid;
      }
      idx_s[tid] = (lo < TIN) ? lo : -1;
    }
    __syncthreads();
    const f32x4* xb = x4 + (size_t)b * (TIN * 96);
    f32x4* ob = out4 + ((size_t)b * TOUT + r0) * 96;
    #pragma unroll 4
    for (int it = 0; it < 24; ++it) {
      int j = it * 512 + tid;                 // 0..12287
      int row = j / 96;
      int c = j - row * 96;
      int id = idx_s[row];
      f32x4 v = {0.f, 0.f, 0.f, 0.f};
      if (id >= 0) v = xb[id * 96 + c];
      __builtin_nontemporal_store(v, ob + j); // out never re-read
    }
    return;
  }

  // ---------------- conv block
  char* As = smem;
  float* stats  = (float*)(smem + 62976);     // [80][8][2]
  float* stats2 = (float*)(smem + 68096);     // [80][2] (mean, rstd)

  const int wave = tid >> 6;        // 0..7
  const int lane = tid & 63;
  const int quad = lane >> 4;
  const int l15  = lane & 15;
  const int wn   = wave * 48;
  const int m0   = bx * 64;
  const int b    = m0 >> 9;         // 64-row tiles never cross batch
  const int t0   = m0 & 511;

  // ---- stage A once: rows 0..67 = x[t0-2 .. t0+65], bf16, swizzled
  for (int p = 0; p < 7; ++p) {
    int ch = p * 512 + tid;
    if (ch < 3264) {                          // 68*48
      int row = ch / 48;
      int ci  = ch - row * 48;
      int t   = t0 - 2 + row;
      u16x8 val;
      if ((unsigned)t >= (unsigned)TIN) {
        val = (u16x8)0;
      } else {
        const f32x4* xr = x4 + ((size_t)(b * TIN + t)) * 96 + ci * 2;
        f32x4 v0 = xr[0], v1 = xr[1];
        val[0] = f2bf(v0[0]); val[1] = f2bf(v0[1]); val[2] = f2bf(v0[2]); val[3] = f2bf(v0[3]);
        val[4] = f2bf(v1[0]); val[5] = f2bf(v1[1]); val[6] = f2bf(v1[2]); val[7] = f2bf(v1[3]);
      }
      unsigned int byte = ((unsigned int)(row * 768 + ci * 16)) ^ (((unsigned)row & 7u) << 4);
      *(u16x8*)(As + byte) = val;
    }
  }
  __syncthreads();

  // ================ conv1: 80-row tile (rows 0..65 used), acc 5x3, no barriers
  f32x4 acc[5][3];
  for (int i = 0; i < 5; ++i)
    for (int j = 0; j < 3; ++j)
      acc[i][j] = (f32x4){0.f, 0.f, 0.f, 0.f};

  {
    const unsigned short* Bb = Wt1 + (size_t)(wn + l15) * D_ + quad * 8;
    bf16x8 bvn[3];
    for (int ni = 0; ni < 3; ++ni)
      bvn[ni] = *(const bf16x8*)(Bb + ni * (16 * D_));
    #pragma unroll 1
    for (int kc = 0; kc < 36; ++kc) {
      bf16x8 bv[3];
      bv[0] = bvn[0]; bv[1] = bvn[1]; bv[2] = bvn[2];
      if (kc < 35) {                          // prefetch next k-step's B frags
        int kn = kc + 1;
        int kw2 = kn / 12, d02 = (kn - kw2 * 12) * 32;
        const unsigned short* Bk = Bb + (size_t)kw2 * (F_ * D_) + d02;
        for (int ni = 0; ni < 3; ++ni)
          bvn[ni] = *(const bf16x8*)(Bk + ni * (16 * D_));
      }
      int kw = kc / 12, d0 = (kc - kw * 12) * 32;
      int rb = l15 + kw;
      unsigned int sw = (((unsigned)rb) & 7u) << 4;
      unsigned int base = (unsigned int)(rb * 768 + d0 * 2 + quad * 16);
      bf16x8 av[5];
      for (int mi = 0; mi < 5; ++mi)
        av[mi] = *(const bf16x8*)(As + ((base + mi * 12288) ^ sw));
      for (int mi = 0; mi < 5; ++mi)
        for (int ni = 0; ni < 3; ++ni)
          acc[mi][ni] = __builtin_amdgcn_mfma_f32_16x16x32_bf16(av[mi], bv[ni], acc[mi][ni], 0, 0, 0);
    }
  }

  // ================ epilogue 1: LN(+bias)+relu -> h1 bf16 into As rows 0..65
  {
    float g1v[3], be1v[3], bb1[3];
    for (int ni = 0; ni < 3; ++ni) {
      int c = wn + ni * 16 + l15;
      g1v[ni] = g1[c]; be1v[ni] = be1[c]; bb1[ni] = b1[c];
    }
    for (int mi = 0; mi < 5; ++mi)
      for (int r = 0; r < 4; ++r) {
        float s = 0.f, ssq = 0.f;
        for (int ni = 0; ni < 3; ++ni) {
          float y = acc[mi][ni][r] + bb1[ni];
          s += y; ssq += y * y;
        }
        for (int off = 1; off < 16; off <<= 1) {   // reduce over quad's 16 lanes
          s   += __shfl_xor(s, off);
          ssq += __shfl_xor(ssq, off);
        }
        if (l15 == 0) {
          int row = mi * 16 + quad * 4 + r;
          stats[(row * 8 + wave) * 2 + 0] = s;
          stats[(row * 8 + wave) * 2 + 1] = ssq;
        }
      }
    __syncthreads();
    if (tid < 80) {
      float s = 0.f, ssq = 0.f;
      for (int w = 0; w < 8; ++w) {
        s   += stats[(tid * 8 + w) * 2 + 0];
        ssq += stats[(tid * 8 + w) * 2 + 1];
      }
      float mean = s * (1.f / 384.f);
      float var  = ssq * (1.f / 384.f) - mean * mean;
      stats2[tid * 2 + 0] = mean;
      stats2[tid * 2 + 1] = rsqrtf(var + 1e-5f);
    }
    __syncthreads();
    for (int mi = 0; mi < 5; ++mi)
      for (int r = 0; r < 4; ++r) {
        int row = mi * 16 + quad * 4 + r;
        if (row < 66) {
          float mean = stats2[row * 2 + 0];
          float rstd = stats2[row * 2 + 1];
          int th = t0 - 1 + row;                         // global h1 time
          bool valid = (unsigned)th < (unsigned)TIN;     // t=-1/512 -> zero pad
          unsigned int hb = (((unsigned)row) & 7u) << 4;
          for (int ni = 0; ni < 3; ++ni) {
            float y = (acc[mi][ni][r] + bb1[ni] - mean) * rstd * g1v[ni] + be1v[ni];
            y = y > 0.f ? y : 0.f;
            if (!valid) y = 0.f;
            unsigned int byte = ((unsigned int)(row * 768 + (wn + ni * 16 + l15) * 2)) ^ hb;
            *(unsigned short*)(As + byte) = f2bf(y);
          }
        }
      }
    __syncthreads();                                     // h1 visible
  }

  // ================ conv2: 64-row tile from h1 (LDS), acc 4x3, no barriers
  f32x4 acc2[4][3];
  for (int i = 0; i < 4; ++i)
    for (int j = 0; j < 3; ++j)
      acc2[i][j] = (f32x4){0.f, 0.f, 0.f, 0.f};

  {
    const unsigned short* Bb = Wt2 + (size_t)(wn + l15) * D_ + quad * 8;
    bf16x8 bvn[3];
    for (int ni = 0; ni < 3; ++ni)
      bvn[ni] = *(const bf16x8*)(Bb + ni * (16 * D_));
    #pragma unroll 1
    for (int kc = 0; kc < 36; ++kc) {
      bf16x8 bv[3];
      bv[0] = bvn[0]; bv[1] = bvn[1]; bv[2] = bvn[2];
      if (kc < 35) {
        int kn = kc + 1;
        int kw2 = kn / 12, d02 = (kn - kw2 * 12) * 32;
        const unsigned short* Bk = Bb + (size_t)kw2 * (F_ * D_) + d02;
        for (int ni = 0; ni < 3; ++ni)
          bvn[ni] = *(const bf16x8*)(Bk + ni * (16 * D_));
      }
      int kw = kc / 12, d0 = (kc - kw * 12) * 32;
      int rb = l15 + kw;                       // h1 row = m + kw
      unsigned int sw = (((unsigned)rb) & 7u) << 4;
      unsigned int base = (unsigned int)(rb * 768 + d0 * 2 + quad * 16);
      bf16x8 av[4];
      for (int mi = 0; mi < 4; ++mi)
        av[mi] = *(const bf16x8*)(As + ((base + mi * 12288) ^ sw));
      for (int mi = 0; mi < 4; ++mi)
        for (int ni = 0; ni < 3; ++ni)
          acc2[mi][ni] = __builtin_amdgcn_mfma_f32_16x16x32_bf16(av[mi], bv[ni], acc2[mi][ni], 0, 0, 0);
    }
  }

  // ================ epilogue 2: LN(+bias)+relu+dot(lin_w)+lb -> dur
  {
    float g2v[3], be2v[3], lwv[3], bb2[3];
    for (int ni = 0; ni < 3; ++ni) {
      int c = wn + ni * 16 + l15;
      g2v[ni] = g2[c]; be2v[ni] = be2[c]; lwv[ni] = lw[c]; bb2[ni] = b2[c];
    }
    for (int mi = 0; mi < 4; ++mi)
      for (int r = 0; r < 4; ++r) {
        float s = 0.f, ssq = 0.f;
        for (int ni = 0; ni < 3; ++ni) {
          float y = acc2[mi][ni][r] + bb2[ni];
          s += y; ssq += y * y;
        }
        for (int off = 1; off < 16; off <<= 1) {
          s   += __shfl_xor(s, off);
          ssq += __shfl_xor(ssq, off);
        }
        if (l15 == 0) {
          int row = mi * 16 + quad * 4 + r;
          stats[(row * 8 + wave) * 2 + 0] = s;
          stats[(row * 8 + wave) * 2 + 1] = ssq;
        }
      }
    __syncthreads();
    if (tid < 64) {
      float s = 0.f, ssq = 0.f;
      for (int w = 0; w < 8; ++w) {
        s   += stats[(tid * 8 + w) * 2 + 0];
        ssq += stats[(tid * 8 + w) * 2 + 1];
      }
      float mean = s * (1.f / 384.f);
      float var  = ssq * (1.f / 384.f) - mean * mean;
      stats2[tid * 2 + 0] = mean;
      stats2[tid * 2 + 1] = rsqrtf(var + 1e-5f);
    }
    __syncthreads();
    for (int mi = 0; mi < 4; ++mi)
      for (int r = 0; r < 4; ++r) {
        int row = mi * 16 + quad * 4 + r;
        float mean = stats2[row * 2 + 0];
        float rstd = stats2[row * 2 + 1];
        float a = 0.f;
        for (int ni = 0; ni < 3; ++ni) {
          float y = (acc2[mi][ni][r] + bb2[ni] - mean) * rstd * g2v[ni] + be2v[ni];
          y = y > 0.f ? y : 0.f;
          a += y * lwv[ni];
        }
        for (int off = 1; off < 16; off <<= 1) a += __shfl_xor(a, off);
        if (l15 == 0) stats[(row * 8 + wave) * 2 + 0] = a;
      }
    __syncthreads();
    if (tid < 64) {
      float a = 0.f;
      for (int w = 0; w < 8; ++w) a += stats[(tid * 8 + w) * 2 + 0];
      dur[m0 + tid] = a + lb[0];
    }
  }
}

// ---------------------------------------------------------------- launch
extern "C" void kernel_launch(void* const* d_in, const int* in_sizes, int n_in,
                              void* d_out, int out_size, void* d_ws, size_t ws_size,
                              hipStream_t stream) {
  const float* x      = (const float*)d_in[0];
  const int*   target = (const int*)d_in[1];
  const float* w1  = (const float*)d_in[3];
  const float* b1  = (const float*)d_in[4];
  const float* g1  = (const float*)d_in[5];
  const float* be1 = (const float*)d_in[6];
  const float* w2  = (const float*)d_in[7];
  const float* b2  = (const float*)d_in[8];
  const float* g2  = (const float*)d_in[9];
  const float* be2 = (const float*)d_in[10];
  const float* lw  = (const float*)d_in[11];
  const float* lb  = (const float*)d_in[12];

  float* out = (float*)d_out;
  float* dur = out + (size_t)B_ * TOUT * D_;   // outputs concatenated flat

  char* ws = (char*)d_ws;
  unsigned short* Wt1 = (unsigned short*)(ws);            // 884,736 B
  unsigned short* Wt2 = (unsigned short*)(ws + 884736);   // 884,736 B

  prep_w<<<dim3(1152), dim3(256), 0, stream>>>(w1, w2, Wt1, Wt2);
  fused<<<dim3(NCONV + NGATH), dim3(512), 0, stream>>>(
      Wt1, Wt2, b1, g1, be1, b2, g2, be2, lw, lb,
      dur, target, (const f32x4*)x, (f32x4*)out);
}